// Round 7
// baseline (229.767 us; speedup 1.0000x reference)
//
#include <hip/hip_runtime.h>
#include <stdint.h>

typedef unsigned short u16;
typedef __attribute__((ext_vector_type(8))) short s16x8;   // 8 x bf16 (4 VGPRs)
typedef __attribute__((ext_vector_type(4))) float f32x4;   // MFMA accumulator

__device__ __forceinline__ f32x4 mfma16x16(s16x8 a, s16x8 b, f32x4 c) {
    return __builtin_amdgcn_mfma_f32_16x16x32_bf16(a, b, c, 0, 0, 0);
}

__device__ __forceinline__ u16 f2bf(float f) {
    union { float f; unsigned u; } c; c.f = f;
    unsigned u = c.u;
    return (u16)((u + 0x7FFFu + ((u >> 16) & 1u)) >> 16);   // RNE
}

// global -> LDS direct 16B load. LDS dest = wave-uniform base + lane*16.
__device__ __forceinline__ void gload16(const void* g, void* l) {
    auto gp = (const __attribute__((address_space(1))) unsigned int*)(g);
    auto lp = (__attribute__((address_space(3))) unsigned int*)(l);
    __builtin_amdgcn_global_load_lds(gp, lp, 16, 0, 0);
}

__device__ __forceinline__ void wave_sync() {
    __builtin_amdgcn_sched_barrier(0);
    asm volatile("s_waitcnt vmcnt(0) lgkmcnt(0)" ::: "memory");
    __builtin_amdgcn_sched_barrier(0);
    __builtin_amdgcn_s_barrier();
    __builtin_amdgcn_sched_barrier(0);
}

// ---------------------------------------------------------------------------
__global__ __launch_bounds__(256) void convert_x(
    const float* __restrict__ src, u16* __restrict__ dst, long n)
{
    const long stride = (long)gridDim.x * 256 * 8;
    for (long i = ((long)blockIdx.x * 256 + threadIdx.x) * 8; i < n; i += stride) {
        const float4 a = *(const float4*)(src + i);
        const float4 b = *(const float4*)(src + i + 4);
        u16 o[8] = { f2bf(a.x), f2bf(a.y), f2bf(a.z), f2bf(a.w),
                     f2bf(b.x), f2bf(b.y), f2bf(b.z), f2bf(b.w) };
        *(s16x8*)(dst + i) = *(const s16x8*)o;
    }
}

__global__ __launch_bounds__(256) void fill_sentinel(float* __restrict__ o, long n)
{
    const long stride = (long)gridDim.x * 256;
    for (long i = (long)blockIdx.x * 256 + threadIdx.x; i < n; i += stride)
        o[i] = 1.0f;
}

__global__ __launch_bounds__(256) void transpose_f32_bf16(
    const float* __restrict__ in, u16* __restrict__ out, int R, int C)
{
    __shared__ u16 t[32][33];
    const int c0 = blockIdx.x * 32, r0 = blockIdx.y * 32;
    const int tx = threadIdx.x & 31, ty = threadIdx.x >> 5;
#pragma unroll
    for (int i = 0; i < 32; i += 8)
        t[ty + i][tx] = f2bf(in[(long)(r0 + ty + i) * C + c0 + tx]);
    __syncthreads();
#pragma unroll
    for (int i = 0; i < 32; i += 8)
        out[(long)(c0 + ty + i) * R + r0 + tx] = t[tx][ty + i];
}

// ---------------------------------------------------------------------------
// 256x256 GEMM, m201-style 4-phase K-tile schedule. BK=64, kk-half split.
// LDS: A = 2dbuf x 2kkhalf x [256 rows][32 cols bf16] (16 KB each) = 64 KB,
//      B same = 64 KB. 8 waves (2M x 4N), per-wave out 128x64, acc[8][4].
// Phase p of tile t: {ds_reads (8 or 4, data published >=1 barrier ago);
//   stage 1 half-tile (2 gloads); [vmcnt(4) gate at ph1/ph3]; bar; lgkm0;
//   setprio1; 16 MFMA; setprio0; bar}.
// Stage map: ph0->(t+1).Ah1, ph1->(t+1).Bh1, ph2->(t+2).Ah0, ph3->(t+2).Bh0.
// Liveness: staged region's last read drained >=2 lgkm0-barriers earlier.
// Gate math (stages #1..6 prologue, tile t adds #7+4t..#10+4t):
//   boundary-gate(t)=vmcnt(4) lands through #6+4t = (t+1).kk0 exactly;
//   mid-gate(t)=vmcnt(4) lands through #8+4(t-1) >= (t).kk1.  t>=NT-3: vmcnt(0).
// ---------------------------------------------------------------------------
template <int FP32OUT, int NT>
__global__ __launch_bounds__(512, 2) void gemm256(
    const u16* __restrict__ A, const u16* __restrict__ BT,
    const float* __restrict__ bias, void* __restrict__ Cout,
    int N, int K)
{
    extern __shared__ char smem[];          // 131072 B
    char* const As = smem;                  // [d*2+h]*16384
    char* const Bs = smem + 65536;

    const int tid  = threadIdx.x;
    const int lane = tid & 63;
    const int wid  = tid >> 6;
    const int rr   = lane & 15, g = lane >> 4;
    const int wr   = wid >> 2;        // 0..1  (M)
    const int wc   = wid & 3;         // 0..3  (N)

    const int nwg = gridDim.x;
    const int gsw = (blockIdx.x & 7) * (nwg >> 3) + (blockIdx.x >> 3);
    const long m0 = (long)(gsw & 63) * 256;
    const long n0 = (long)(gsw >> 6) * 256;

    // staging: thread covers row (tid>>2)+r*128, 16B chunk cl (pre-swizzled)
    const int cl = (tid & 3) ^ ((tid >> 3) & 3);
    const u16* pA0 = A  + (m0 + (tid >> 2)) * (long)K + cl * 8;
    const u16* pA1 = pA0 + 128 * (long)K;
    const u16* pB0 = BT + (n0 + (tid >> 2)) * (long)K + cl * 8;
    const u16* pB1 = pB0 + 128 * (long)K;
    const int sdst = wid * 1024;

    // fragment read: row*64 + swizzled 16B chunk
    const int xg    = (g ^ ((rr >> 1) & 3)) << 4;
    const int arow  = (wr * 128 + rr) * 64 + xg;   // + mf*1024
    const int brow  = (wc * 64  + rr) * 64 + xg;   // + nf*1024

#define STA(tt, h) { const long c_ = (long)(tt) * 64 + (h) * 32;              \
        char* d_ = As + (((tt) & 1) * 2 + (h)) * 16384 + sdst;                \
        gload16(pA0 + c_, d_); gload16(pA1 + c_, d_ + 8192); }
#define STB(tt, h) { const long c_ = (long)(tt) * 64 + (h) * 32;              \
        char* d_ = Bs + (((tt) & 1) * 2 + (h)) * 16384 + sdst;                \
        gload16(pB0 + c_, d_); gload16(pB1 + c_, d_ + 8192); }
#define BAR() { __builtin_amdgcn_sched_barrier(0); __builtin_amdgcn_s_barrier(); }
#define LGKM0() { asm volatile("s_waitcnt lgkmcnt(0)" ::: "memory");          \
        __builtin_amdgcn_sched_barrier(0); }

    f32x4 acc[8][4] = {};

    // prologue: stages #1..6 = t0.Ah0, t0.Bh0, t0.Ah1, t0.Bh1, t1.Ah0, t1.Bh0
    STA(0, 0); STB(0, 0); STA(0, 1); STB(0, 1); STA(1, 0); STB(1, 0);
    asm volatile("s_waitcnt vmcnt(4)" ::: "memory");   // t0 fully landed
    BAR();

    for (int t = 0; t < NT; ++t) {
        const int ab = (t & 1) * 32768;                // dbuf base (A and B)
        const bool tl = (t >= NT - 3);
        s16x8 bf[4], af[4];

        // ---- ph0: read B kk0 + A[m0-3] kk0; stage (t+1).Ah1
#pragma unroll
        for (int n = 0; n < 4; ++n)
            bf[n] = *(const s16x8*)(Bs + ab + brow + n * 1024);
#pragma unroll
        for (int m = 0; m < 4; ++m)
            af[m] = *(const s16x8*)(As + ab + arow + m * 1024);
        if (t + 1 < NT) STA(t + 1, 1);
        BAR(); LGKM0();
        __builtin_amdgcn_s_setprio(1);
#pragma unroll
        for (int m = 0; m < 4; ++m)
#pragma unroll
            for (int n = 0; n < 4; ++n)
                acc[m][n] = mfma16x16(af[m], bf[n], acc[m][n]);
        __builtin_amdgcn_s_setprio(0);
        BAR();

        // ---- ph1: read A[m4-7] kk0; stage (t+1).Bh1; mid-gate
#pragma unroll
        for (int m = 0; m < 4; ++m)
            af[m] = *(const s16x8*)(As + ab + arow + (m + 4) * 1024);
        if (t + 1 < NT) STB(t + 1, 1);
        if (tl) { asm volatile("s_waitcnt vmcnt(0)" ::: "memory"); }
        else    { asm volatile("s_waitcnt vmcnt(4)" ::: "memory"); }
        BAR(); LGKM0();
        __builtin_amdgcn_s_setprio(1);
#pragma unroll
        for (int m = 0; m < 4; ++m)
#pragma unroll
            for (int n = 0; n < 4; ++n)
                acc[m + 4][n] = mfma16x16(af[m], bf[n], acc[m + 4][n]);
        __builtin_amdgcn_s_setprio(0);
        BAR();

        // ---- ph2: read B kk1 + A[m0-3] kk1; stage (t+2).Ah0
#pragma unroll
        for (int n = 0; n < 4; ++n)
            bf[n] = *(const s16x8*)(Bs + ab + 16384 + brow + n * 1024);
#pragma unroll
        for (int m = 0; m < 4; ++m)
            af[m] = *(const s16x8*)(As + ab + 16384 + arow + m * 1024);
        if (t + 2 < NT) STA(t + 2, 0);
        BAR(); LGKM0();
        __builtin_amdgcn_s_setprio(1);
#pragma unroll
        for (int m = 0; m < 4; ++m)
#pragma unroll
            for (int n = 0; n < 4; ++n)
                acc[m][n] = mfma16x16(af[m], bf[n], acc[m][n]);
        __builtin_amdgcn_s_setprio(0);
        BAR();

        // ---- ph3: read A[m4-7] kk1; stage (t+2).Bh0; boundary-gate
#pragma unroll
        for (int m = 0; m < 4; ++m)
            af[m] = *(const s16x8*)(As + ab + 16384 + arow + (m + 4) * 1024);
        if (t + 2 < NT) STB(t + 2, 0);
        if (tl) { asm volatile("s_waitcnt vmcnt(0)" ::: "memory"); }
        else    { asm volatile("s_waitcnt vmcnt(4)" ::: "memory"); }
        BAR(); LGKM0();
        __builtin_amdgcn_s_setprio(1);
#pragma unroll
        for (int m = 0; m < 4; ++m)
#pragma unroll
            for (int n = 0; n < 4; ++n)
                acc[m + 4][n] = mfma16x16(af[m], bf[n], acc[m + 4][n]);
        __builtin_amdgcn_s_setprio(0);
        BAR();
    }
#undef STA
#undef STB
#undef BAR
#undef LGKM0

    // epilogue
#pragma unroll
    for (int n = 0; n < 4; ++n) {
        const long col = n0 + wc * 64 + n * 16 + rr;
        const float bv = bias[col];
#pragma unroll
        for (int m = 0; m < 8; ++m) {
            const long rb = m0 + wr * 128 + m * 16 + g * 4;
#pragma unroll
            for (int r = 0; r < 4; ++r) {
                const float v = acc[m][n][r] + bv;
                if (FP32OUT) ((float*)Cout)[(rb + r) * N + col] = v;
                else         ((u16*)Cout)[(rb + r) * N + col] = f2bf(v);
            }
        }
    }
}

// ---------------------------------------------------------------------------
// Fallback GEMM (proven R4 path): 128x128 tile, BK=64, 2-barrier loop.
// ---------------------------------------------------------------------------
template <int FP32OUT>
__global__ __launch_bounds__(256) void gemm_bt_bias(
    const u16* __restrict__ A, const u16* __restrict__ BT,
    const float* __restrict__ bias, void* __restrict__ Cout,
    int M, int N, int K)
{
    __shared__ u16 As[128 * 64];
    __shared__ u16 Bs[128 * 64];
    const int tid  = threadIdx.x;
    const int lane = tid & 63;
    const int wid  = tid >> 6;
    const int rr   = lane & 15, g = lane >> 4;
    const int wm   = (wid >> 1) << 6;
    const int wn   = (wid & 1) << 6;
    const long m0  = (long)blockIdx.y * 128;
    const long n0  = (long)blockIdx.x * 128;
    const int srow   = tid >> 3;
    const int schunk = (tid & 7) ^ (srow & 7);

    f32x4 acc[4][4] = {};

    for (int k0 = 0; k0 < K; k0 += 64) {
#pragma unroll
        for (int q = 0; q < 4; ++q) {
            const int row = q * 32 + srow;
            gload16(A  + (m0 + row) * K + k0 + schunk * 8,
                    (char*)As + q * 4096 + wid * 1024);
            gload16(BT + (n0 + row) * K + k0 + schunk * 8,
                    (char*)Bs + q * 4096 + wid * 1024);
        }
        __syncthreads();
#pragma unroll
        for (int kk = 0; kk < 2; ++kk) {
            s16x8 af[4], bfr[4];
#pragma unroll
            for (int i = 0; i < 4; ++i) {
                const int rowa = wm + i * 16 + rr;
                af[i] = *(const s16x8*)((const char*)As + rowa * 128 +
                         ((kk * 64 + g * 16) ^ ((rowa & 7) << 4)));
                const int rowb = wn + i * 16 + rr;
                bfr[i] = *(const s16x8*)((const char*)Bs + rowb * 128 +
                         ((kk * 64 + g * 16) ^ ((rowb & 7) << 4)));
            }
#pragma unroll
            for (int i = 0; i < 4; ++i)
#pragma unroll
                for (int j = 0; j < 4; ++j)
                    acc[i][j] = mfma16x16(af[i], bfr[j], acc[i][j]);
        }
        __syncthreads();
    }

#pragma unroll
    for (int j = 0; j < 4; ++j) {
        const long col = n0 + wn + j * 16 + rr;
        const float bv = bias[col];
#pragma unroll
        for (int i = 0; i < 4; ++i)
#pragma unroll
            for (int r = 0; r < 4; ++r) {
                const long rowg = m0 + wm + i * 16 + g * 4 + r;
                const float v = acc[i][j][r] + bv;
                if (FP32OUT) ((float*)Cout)[rowg * N + col] = v;
                else         ((u16*)Cout)[rowg * N + col] = f2bf(v);
            }
    }
}

// ---------------------------------------------------------------------------
// Factored attention: one wave per (b, h, p). Attention over NB=64 blocks.
// ---------------------------------------------------------------------------
__global__ __launch_bounds__(64) void attn_blocks(
    const u16* __restrict__ qkv, u16* __restrict__ o)
{
    __shared__ u16 Vlds[64 * 64];
    __shared__ u16 Plds[64 * 72];
    const int bid = blockIdx.x;
    const int b = bid >> 11;
    const int h = (bid >> 7) & 15;
    const int p = bid & 127;
    const int lane = threadIdx.x;
    const int rr = lane & 15, g = lane >> 4;
    const long NSTR = 128L * 3072;
    const long base = ((long)b * 8192 + p) * 3072 + h * 64;

    {
        const int vrow = lane >> 3;
        const int vchunk = (lane & 7) ^ (vrow & 7);
#pragma unroll
        for (int q = 0; q < 8; ++q)
            gload16(qkv + base + (long)(q * 8 + vrow) * NSTR + 2048 + vchunk * 8,
                    (char*)Vlds + q * 1024);
    }

    s16x8 kf[4][2], qf[4][2];
#pragma unroll
    for (int t = 0; t < 4; ++t)
#pragma unroll
        for (int ks = 0; ks < 2; ++ks) {
            const long roff = base + (long)(t * 16 + rr) * NSTR + ks * 32 + g * 8;
            kf[t][ks] = *(const s16x8*)(qkv + roff + 1024);
            qf[t][ks] = *(const s16x8*)(qkv + roff);
        }

    f32x4 T[4][4] = {};
#pragma unroll
    for (int ks = 0; ks < 2; ++ks)
#pragma unroll
        for (int i = 0; i < 4; ++i)
#pragma unroll
            for (int jn = 0; jn < 4; ++jn)
                T[i][jn] = mfma16x16(kf[i][ks], qf[jn][ks], T[i][jn]);

    const float scale = 0.125f;
#pragma unroll
    for (int jn = 0; jn < 4; ++jn) {
        const int n = jn * 16 + rr;
        float pv[16];
        float mx = -3e38f;
#pragma unroll
        for (int i = 0; i < 4; ++i)
#pragma unroll
            for (int r = 0; r < 4; ++r) {
                const int m = i * 16 + g * 4 + r;
                const float s = (m <= n) ? T[i][jn][r] * scale : -3e38f;
                pv[i * 4 + r] = s;
                mx = fmaxf(mx, s);
            }
        mx = fmaxf(mx, __shfl_xor(mx, 16));
        mx = fmaxf(mx, __shfl_xor(mx, 32));
        float sum = 0.f;
#pragma unroll
        for (int t = 0; t < 16; ++t) {
            const float e = (pv[t] > -1e30f) ? __expf(pv[t] - mx) : 0.f;
            pv[t] = e;
            sum += e;
        }
        sum += __shfl_xor(sum, 16);
        sum += __shfl_xor(sum, 32);
        const float inv = 1.f / sum;
#pragma unroll
        for (int i = 0; i < 4; ++i)
#pragma unroll
            for (int rp = 0; rp < 2; ++rp) {
                const int m = i * 16 + g * 4 + rp * 2;
                const unsigned lo = f2bf(pv[i * 4 + rp * 2] * inv);
                const unsigned hi = f2bf(pv[i * 4 + rp * 2 + 1] * inv);
                *(unsigned*)((char*)Plds + n * 144 + m * 2) = lo | (hi << 16);
            }
    }

    wave_sync();

    f32x4 O[4][4] = {};
#pragma unroll
    for (int ks = 0; ks < 2; ++ks) {
        s16x8 pa[4];
#pragma unroll
        for (int in = 0; in < 4; ++in)
            pa[in] = *(const s16x8*)((const char*)Plds +
                      (in * 16 + rr) * 144 + ks * 64 + g * 16);
#pragma unroll
        for (int jd = 0; jd < 4; ++jd) {
            s16x8 vb;
#pragma unroll
            for (int j = 0; j < 8; ++j) {
                const int k = ks * 32 + g * 8 + j;
                const int byte = (k * 128 + (jd * 16 + rr) * 2) ^ ((k & 7) << 4);
                vb[j] = *(const short*)((const char*)Vlds + byte);
            }
#pragma unroll
            for (int in = 0; in < 4; ++in)
                O[in][jd] = mfma16x16(pa[in], vb, O[in][jd]);
        }
    }

    const long obase = ((long)b * 8192 + p) * 1024 + h * 64;
#pragma unroll
    for (int in = 0; in < 4; ++in)
#pragma unroll
        for (int jd = 0; jd < 4; ++jd)
#pragma unroll
            for (int r = 0; r < 4; ++r) {
                const long n = in * 16 + g * 4 + r;
                const long d = jd * 16 + rr;
                o[obase + n * (128L * 1024) + d] = f2bf(O[in][jd][r]);
            }
}

// ---------------------------------------------------------------------------
extern "C" void kernel_launch(void* const* d_in, const int* in_sizes, int n_in,
                              void* d_out, int out_size, void* d_ws, size_t ws_size,
                              hipStream_t stream) {
    const float* x    = (const float*)d_in[0];
    const float* Wqkv = (const float*)d_in[1];
    const float* bq   = (const float*)d_in[2];
    const float* Wout = (const float*)d_in[3];
    const float* bo   = (const float*)d_in[4];

    char* ws = (char*)d_ws;
    u16* xb    = (u16*)(ws);                 // 33,554,432 B
    u16* qkv   = (u16*)(ws +  33554432L);    // 100,663,296 B
    u16* ob    = (u16*)(ws + 134217728L);    // 33,554,432 B
    u16* WqkvT = (u16*)(ws + 167772160L);    // 6,291,456 B
    u16* WoutT = (u16*)(ws + 174063616L);    // 2,097,152 B
    const size_t NEEDED = 176160768UL;

    if (ws_size < NEEDED) {
        fill_sentinel<<<2048, 256, 0, stream>>>((float*)d_out, (long)out_size);
        return;
    }

    bool deep = true;
    if (hipFuncSetAttribute(reinterpret_cast<const void*>(&gemm256<0, 16>),
                            hipFuncAttributeMaxDynamicSharedMemorySize,
                            131072) != hipSuccess) deep = false;
    if (hipFuncSetAttribute(reinterpret_cast<const void*>(&gemm256<1, 16>),
                            hipFuncAttributeMaxDynamicSharedMemorySize,
                            131072) != hipSuccess) deep = false;

    convert_x<<<2048, 256, 0, stream>>>(x, xb, 16777216L);
    transpose_f32_bf16<<<dim3(96, 32), 256, 0, stream>>>(Wqkv, WqkvT, 1024, 3072);
    transpose_f32_bf16<<<dim3(32, 32), 256, 0, stream>>>(Wout, WoutT, 1024, 1024);

    // qkv = x @ Wqkv + bqkv   (M=16384, N=3072, K=1024)
    if (deep)
        gemm256<0, 16><<<768, 512, 131072, stream>>>(xb, WqkvT, bq, qkv,
                                                     3072, 1024);
    else
        gemm_bt_bias<0><<<dim3(24, 128), 256, 0, stream>>>(xb, WqkvT, bq, qkv,
                                                           16384, 3072, 1024);

    attn_blocks<<<4096, 64, 0, stream>>>(qkv, ob);

    // out = o @ Wout + bout   (M=16384, N=1024, K=1024)
    if (deep)
        gemm256<1, 16><<<256, 512, 131072, stream>>>(ob, WoutT, bo, d_out,
                                                     1024, 1024);
    else
        gemm_bt_bias<1><<<dim3(8, 128), 256, 0, stream>>>(ob, WoutT, bo, d_out,
                                                          16384, 1024, 1024);
}

// Round 8
// 207.122 us; speedup vs baseline: 1.1093x; 1.1093x over previous
//
#include <hip/hip_runtime.h>
#include <stdint.h>

typedef unsigned short u16;
typedef __attribute__((ext_vector_type(8))) short s16x8;   // 8 x bf16 (4 VGPRs)
typedef __attribute__((ext_vector_type(4))) float f32x4;   // MFMA accumulator

__device__ __forceinline__ f32x4 mfma16x16(s16x8 a, s16x8 b, f32x4 c) {
    return __builtin_amdgcn_mfma_f32_16x16x32_bf16(a, b, c, 0, 0, 0);
}

__device__ __forceinline__ u16 f2bf(float f) {
    union { float f; unsigned u; } c; c.f = f;
    unsigned u = c.u;
    return (u16)((u + 0x7FFFu + ((u >> 16) & 1u)) >> 16);   // RNE
}

// global -> LDS direct 16B load. LDS dest = wave-uniform base + lane*16.
__device__ __forceinline__ void gload16(const void* g, void* l) {
    auto gp = (const __attribute__((address_space(1))) unsigned int*)(g);
    auto lp = (__attribute__((address_space(3))) unsigned int*)(l);
    __builtin_amdgcn_global_load_lds(gp, lp, 16, 0, 0);
}

__device__ __forceinline__ void wave_sync() {
    __builtin_amdgcn_sched_barrier(0);
    asm volatile("s_waitcnt vmcnt(0) lgkmcnt(0)" ::: "memory");
    __builtin_amdgcn_sched_barrier(0);
    __builtin_amdgcn_s_barrier();
    __builtin_amdgcn_sched_barrier(0);
}

// ---------------------------------------------------------------------------
__global__ __launch_bounds__(256) void convert_x(
    const float* __restrict__ src, u16* __restrict__ dst, long n)
{
    const long stride = (long)gridDim.x * 256 * 8;
    for (long i = ((long)blockIdx.x * 256 + threadIdx.x) * 8; i < n; i += stride) {
        const float4 a = *(const float4*)(src + i);
        const float4 b = *(const float4*)(src + i + 4);
        u16 o[8] = { f2bf(a.x), f2bf(a.y), f2bf(a.z), f2bf(a.w),
                     f2bf(b.x), f2bf(b.y), f2bf(b.z), f2bf(b.w) };
        *(s16x8*)(dst + i) = *(const s16x8*)o;
    }
}

__global__ __launch_bounds__(256) void fill_sentinel(float* __restrict__ o, long n)
{
    const long stride = (long)gridDim.x * 256;
    for (long i = (long)blockIdx.x * 256 + threadIdx.x; i < n; i += stride)
        o[i] = 1.0f;
}

__global__ __launch_bounds__(256) void transpose_f32_bf16(
    const float* __restrict__ in, u16* __restrict__ out, int R, int C)
{
    __shared__ u16 t[32][33];
    const int c0 = blockIdx.x * 32, r0 = blockIdx.y * 32;
    const int tx = threadIdx.x & 31, ty = threadIdx.x >> 5;
#pragma unroll
    for (int i = 0; i < 32; i += 8)
        t[ty + i][tx] = f2bf(in[(long)(r0 + ty + i) * C + c0 + tx]);
    __syncthreads();
#pragma unroll
    for (int i = 0; i < 32; i += 8)
        out[(long)(c0 + ty + i) * R + r0 + tx] = t[tx][ty + i];
}

// ---------------------------------------------------------------------------
// 256x256 GEMM, 4-phase K-tile pipeline (BK=64, kk-half split, dbuf).
// R8 changes vs R7 (traffic fixes -- schedule untouched):
//  * grid swizzle n-fastest within XCD: m0 = gsw/NBN, n0 = gsw%NBN ->
//    per-XCD A-footprint 8 m-strips = 4 MB (L2-resident) instead of
//    streaming all of A per n-column (FETCH was 5x ideal).
//  * epilogue n-innermost: the 4 column-chunks (32B bf16 / 64B fp32) that
//    complete each cache line are issued back-to-back -> L2 write-merge
//    (WRITE was 173 MB vs 100 MB ideal from partial-line RMW).
// ---------------------------------------------------------------------------
template <int FP32OUT, int NT, int NBN>
__global__ __launch_bounds__(512, 2) void gemm256(
    const u16* __restrict__ A, const u16* __restrict__ BT,
    const float* __restrict__ bias, void* __restrict__ Cout,
    int N, int K)
{
    extern __shared__ char smem[];          // 131072 B
    char* const As = smem;                  // [d*2+h]*16384
    char* const Bs = smem + 65536;

    const int tid  = threadIdx.x;
    const int lane = tid & 63;
    const int wid  = tid >> 6;
    const int rr   = lane & 15, g = lane >> 4;
    const int wr   = wid >> 2;        // 0..1  (M)
    const int wc   = wid & 3;         // 0..3  (N)

    const int nwg = gridDim.x;
    const int gsw = (blockIdx.x & 7) * (nwg >> 3) + (blockIdx.x >> 3);
    const long m0 = (long)(gsw / NBN) * 256;   // n-fastest within XCD
    const long n0 = (long)(gsw % NBN) * 256;

    // staging: thread covers row (tid>>2)+r*128, 16B chunk cl (pre-swizzled)
    const int cl = (tid & 3) ^ ((tid >> 3) & 3);
    const u16* pA0 = A  + (m0 + (tid >> 2)) * (long)K + cl * 8;
    const u16* pA1 = pA0 + 128 * (long)K;
    const u16* pB0 = BT + (n0 + (tid >> 2)) * (long)K + cl * 8;
    const u16* pB1 = pB0 + 128 * (long)K;
    const int sdst = wid * 1024;

    // fragment read: row*64 + swizzled 16B chunk
    const int xg    = (g ^ ((rr >> 1) & 3)) << 4;
    const int arow  = (wr * 128 + rr) * 64 + xg;   // + mf*1024
    const int brow  = (wc * 64  + rr) * 64 + xg;   // + nf*1024

#define STA(tt, h) { const long c_ = (long)(tt) * 64 + (h) * 32;              \
        char* d_ = As + (((tt) & 1) * 2 + (h)) * 16384 + sdst;                \
        gload16(pA0 + c_, d_); gload16(pA1 + c_, d_ + 8192); }
#define STB(tt, h) { const long c_ = (long)(tt) * 64 + (h) * 32;              \
        char* d_ = Bs + (((tt) & 1) * 2 + (h)) * 16384 + sdst;                \
        gload16(pB0 + c_, d_); gload16(pB1 + c_, d_ + 8192); }
#define BAR() { __builtin_amdgcn_sched_barrier(0); __builtin_amdgcn_s_barrier(); }
#define LGKM0() { asm volatile("s_waitcnt lgkmcnt(0)" ::: "memory");          \
        __builtin_amdgcn_sched_barrier(0); }

    f32x4 acc[8][4] = {};

    // prologue: t0.Ah0, t0.Bh0, t0.Ah1, t0.Bh1, t1.Ah0, t1.Bh0
    STA(0, 0); STB(0, 0); STA(0, 1); STB(0, 1); STA(1, 0); STB(1, 0);
    asm volatile("s_waitcnt vmcnt(4)" ::: "memory");   // t0 fully landed
    BAR();

    for (int t = 0; t < NT; ++t) {
        const int ab = (t & 1) * 32768;                // dbuf base (A and B)
        const bool tl = (t >= NT - 3);
        s16x8 bf[4], af[4];

        // ---- ph0: read B kk0 + A[m0-3] kk0; stage (t+1).Ah1
#pragma unroll
        for (int n = 0; n < 4; ++n)
            bf[n] = *(const s16x8*)(Bs + ab + brow + n * 1024);
#pragma unroll
        for (int m = 0; m < 4; ++m)
            af[m] = *(const s16x8*)(As + ab + arow + m * 1024);
        if (t + 1 < NT) STA(t + 1, 1);
        BAR(); LGKM0();
        __builtin_amdgcn_s_setprio(1);
#pragma unroll
        for (int m = 0; m < 4; ++m)
#pragma unroll
            for (int n = 0; n < 4; ++n)
                acc[m][n] = mfma16x16(af[m], bf[n], acc[m][n]);
        __builtin_amdgcn_s_setprio(0);
        BAR();

        // ---- ph1: read A[m4-7] kk0; stage (t+1).Bh1; mid-gate
#pragma unroll
        for (int m = 0; m < 4; ++m)
            af[m] = *(const s16x8*)(As + ab + arow + (m + 4) * 1024);
        if (t + 1 < NT) STB(t + 1, 1);
        if (tl) { asm volatile("s_waitcnt vmcnt(0)" ::: "memory"); }
        else    { asm volatile("s_waitcnt vmcnt(4)" ::: "memory"); }
        BAR(); LGKM0();
        __builtin_amdgcn_s_setprio(1);
#pragma unroll
        for (int m = 0; m < 4; ++m)
#pragma unroll
            for (int n = 0; n < 4; ++n)
                acc[m + 4][n] = mfma16x16(af[m], bf[n], acc[m + 4][n]);
        __builtin_amdgcn_s_setprio(0);
        BAR();

        // ---- ph2: read B kk1 + A[m0-3] kk1; stage (t+2).Ah0
#pragma unroll
        for (int n = 0; n < 4; ++n)
            bf[n] = *(const s16x8*)(Bs + ab + 16384 + brow + n * 1024);
#pragma unroll
        for (int m = 0; m < 4; ++m)
            af[m] = *(const s16x8*)(As + ab + 16384 + arow + m * 1024);
        if (t + 2 < NT) STA(t + 2, 0);
        BAR(); LGKM0();
        __builtin_amdgcn_s_setprio(1);
#pragma unroll
        for (int m = 0; m < 4; ++m)
#pragma unroll
            for (int n = 0; n < 4; ++n)
                acc[m][n] = mfma16x16(af[m], bf[n], acc[m][n]);
        __builtin_amdgcn_s_setprio(0);
        BAR();

        // ---- ph3: read A[m4-7] kk1; stage (t+2).Bh0; boundary-gate
#pragma unroll
        for (int m = 0; m < 4; ++m)
            af[m] = *(const s16x8*)(As + ab + 16384 + arow + (m + 4) * 1024);
        if (t + 2 < NT) STB(t + 2, 0);
        if (tl) { asm volatile("s_waitcnt vmcnt(0)" ::: "memory"); }
        else    { asm volatile("s_waitcnt vmcnt(4)" ::: "memory"); }
        BAR(); LGKM0();
        __builtin_amdgcn_s_setprio(1);
#pragma unroll
        for (int m = 0; m < 4; ++m)
#pragma unroll
            for (int n = 0; n < 4; ++n)
                acc[m + 4][n] = mfma16x16(af[m], bf[n], acc[m + 4][n]);
        __builtin_amdgcn_s_setprio(0);
        BAR();
    }
#undef STA
#undef STB
#undef BAR
#undef LGKM0

    // epilogue: n innermost so the 4 chunks completing each cache line are
    // issued back-to-back (L2 write-merge).
    float bv[4];
#pragma unroll
    for (int n = 0; n < 4; ++n)
        bv[n] = bias[n0 + wc * 64 + n * 16 + rr];
#pragma unroll
    for (int m = 0; m < 8; ++m) {
        const long rb = m0 + wr * 128 + m * 16 + g * 4;
#pragma unroll
        for (int r = 0; r < 4; ++r) {
            const long rowoff = (rb + r) * N + n0 + wc * 64 + rr;
#pragma unroll
            for (int n = 0; n < 4; ++n) {
                const float v = acc[m][n][r] + bv[n];
                if (FP32OUT) ((float*)Cout)[rowoff + n * 16] = v;
                else         ((u16*)Cout)[rowoff + n * 16] = f2bf(v);
            }
        }
    }
}

// ---------------------------------------------------------------------------
// Fallback GEMM (proven R4 path): 128x128 tile, BK=64, 2-barrier loop.
// ---------------------------------------------------------------------------
template <int FP32OUT>
__global__ __launch_bounds__(256) void gemm_bt_bias(
    const u16* __restrict__ A, const u16* __restrict__ BT,
    const float* __restrict__ bias, void* __restrict__ Cout,
    int M, int N, int K)
{
    __shared__ u16 As[128 * 64];
    __shared__ u16 Bs[128 * 64];
    const int tid  = threadIdx.x;
    const int lane = tid & 63;
    const int wid  = tid >> 6;
    const int rr   = lane & 15, g = lane >> 4;
    const int wm   = (wid >> 1) << 6;
    const int wn   = (wid & 1) << 6;
    const long m0  = (long)blockIdx.y * 128;
    const long n0  = (long)blockIdx.x * 128;
    const int srow   = tid >> 3;
    const int schunk = (tid & 7) ^ (srow & 7);

    f32x4 acc[4][4] = {};

    for (int k0 = 0; k0 < K; k0 += 64) {
#pragma unroll
        for (int q = 0; q < 4; ++q) {
            const int row = q * 32 + srow;
            gload16(A  + (m0 + row) * K + k0 + schunk * 8,
                    (char*)As + q * 4096 + wid * 1024);
            gload16(BT + (n0 + row) * K + k0 + schunk * 8,
                    (char*)Bs + q * 4096 + wid * 1024);
        }
        __syncthreads();
#pragma unroll
        for (int kk = 0; kk < 2; ++kk) {
            s16x8 af[4], bfr[4];
#pragma unroll
            for (int i = 0; i < 4; ++i) {
                const int rowa = wm + i * 16 + rr;
                af[i] = *(const s16x8*)((const char*)As + rowa * 128 +
                         ((kk * 64 + g * 16) ^ ((rowa & 7) << 4)));
                const int rowb = wn + i * 16 + rr;
                bfr[i] = *(const s16x8*)((const char*)Bs + rowb * 128 +
                         ((kk * 64 + g * 16) ^ ((rowb & 7) << 4)));
            }
#pragma unroll
            for (int i = 0; i < 4; ++i)
#pragma unroll
                for (int j = 0; j < 4; ++j)
                    acc[i][j] = mfma16x16(af[i], bfr[j], acc[i][j]);
        }
        __syncthreads();
    }

#pragma unroll
    for (int i = 0; i < 4; ++i)
#pragma unroll
        for (int r = 0; r < 4; ++r) {
            const long rowg = m0 + wm + i * 16 + g * 4 + r;
#pragma unroll
            for (int j = 0; j < 4; ++j) {
                const long col = n0 + wn + j * 16 + rr;
                const float v = acc[i][j][r] + bias[col];
                if (FP32OUT) ((float*)Cout)[rowg * N + col] = v;
                else         ((u16*)Cout)[rowg * N + col] = f2bf(v);
            }
        }
}

// ---------------------------------------------------------------------------
// Factored attention: one wave per (b, h, p). Attention over NB=64 blocks.
// ---------------------------------------------------------------------------
__global__ __launch_bounds__(64) void attn_blocks(
    const u16* __restrict__ qkv, u16* __restrict__ o)
{
    __shared__ u16 Vlds[64 * 64];
    __shared__ u16 Plds[64 * 72];
    const int bid = blockIdx.x;
    const int b = bid >> 11;
    const int h = (bid >> 7) & 15;
    const int p = bid & 127;
    const int lane = threadIdx.x;
    const int rr = lane & 15, g = lane >> 4;
    const long NSTR = 128L * 3072;
    const long base = ((long)b * 8192 + p) * 3072 + h * 64;

    {
        const int vrow = lane >> 3;
        const int vchunk = (lane & 7) ^ (vrow & 7);
#pragma unroll
        for (int q = 0; q < 8; ++q)
            gload16(qkv + base + (long)(q * 8 + vrow) * NSTR + 2048 + vchunk * 8,
                    (char*)Vlds + q * 1024);
    }

    s16x8 kf[4][2], qf[4][2];
#pragma unroll
    for (int t = 0; t < 4; ++t)
#pragma unroll
        for (int ks = 0; ks < 2; ++ks) {
            const long roff = base + (long)(t * 16 + rr) * NSTR + ks * 32 + g * 8;
            kf[t][ks] = *(const s16x8*)(qkv + roff + 1024);
            qf[t][ks] = *(const s16x8*)(qkv + roff);
        }

    f32x4 T[4][4] = {};
#pragma unroll
    for (int ks = 0; ks < 2; ++ks)
#pragma unroll
        for (int i = 0; i < 4; ++i)
#pragma unroll
            for (int jn = 0; jn < 4; ++jn)
                T[i][jn] = mfma16x16(kf[i][ks], qf[jn][ks], T[i][jn]);

    const float scale = 0.125f;
#pragma unroll
    for (int jn = 0; jn < 4; ++jn) {
        const int n = jn * 16 + rr;
        float pv[16];
        float mx = -3e38f;
#pragma unroll
        for (int i = 0; i < 4; ++i)
#pragma unroll
            for (int r = 0; r < 4; ++r) {
                const int m = i * 16 + g * 4 + r;
                const float s = (m <= n) ? T[i][jn][r] * scale : -3e38f;
                pv[i * 4 + r] = s;
                mx = fmaxf(mx, s);
            }
        mx = fmaxf(mx, __shfl_xor(mx, 16));
        mx = fmaxf(mx, __shfl_xor(mx, 32));
        float sum = 0.f;
#pragma unroll
        for (int t = 0; t < 16; ++t) {
            const float e = (pv[t] > -1e30f) ? __expf(pv[t] - mx) : 0.f;
            pv[t] = e;
            sum += e;
        }
        sum += __shfl_xor(sum, 16);
        sum += __shfl_xor(sum, 32);
        const float inv = 1.f / sum;
#pragma unroll
        for (int i = 0; i < 4; ++i)
#pragma unroll
            for (int rp = 0; rp < 2; ++rp) {
                const int m = i * 16 + g * 4 + rp * 2;
                const unsigned lo = f2bf(pv[i * 4 + rp * 2] * inv);
                const unsigned hi = f2bf(pv[i * 4 + rp * 2 + 1] * inv);
                *(unsigned*)((char*)Plds + n * 144 + m * 2) = lo | (hi << 16);
            }
    }

    wave_sync();

    f32x4 O[4][4] = {};
#pragma unroll
    for (int ks = 0; ks < 2; ++ks) {
        s16x8 pa[4];
#pragma unroll
        for (int in = 0; in < 4; ++in)
            pa[in] = *(const s16x8*)((const char*)Plds +
                      (in * 16 + rr) * 144 + ks * 64 + g * 16);
#pragma unroll
        for (int jd = 0; jd < 4; ++jd) {
            s16x8 vb;
#pragma unroll
            for (int j = 0; j < 8; ++j) {
                const int k = ks * 32 + g * 8 + j;
                const int byte = (k * 128 + (jd * 16 + rr) * 2) ^ ((k & 7) << 4);
                vb[j] = *(const short*)((const char*)Vlds + byte);
            }
#pragma unroll
            for (int in = 0; in < 4; ++in)
                O[in][jd] = mfma16x16(pa[in], vb, O[in][jd]);
        }
    }

    const long obase = ((long)b * 8192 + p) * 1024 + h * 64;
#pragma unroll
    for (int in = 0; in < 4; ++in)
#pragma unroll
        for (int r = 0; r < 4; ++r) {
            const long n = in * 16 + g * 4 + r;
#pragma unroll
            for (int jd = 0; jd < 4; ++jd) {
                const long d = jd * 16 + rr;
                o[obase + n * (128L * 1024) + d] = f2bf(O[in][jd][r]);
            }
        }
}

// ---------------------------------------------------------------------------
extern "C" void kernel_launch(void* const* d_in, const int* in_sizes, int n_in,
                              void* d_out, int out_size, void* d_ws, size_t ws_size,
                              hipStream_t stream) {
    const float* x    = (const float*)d_in[0];
    const float* Wqkv = (const float*)d_in[1];
    const float* bq   = (const float*)d_in[2];
    const float* Wout = (const float*)d_in[3];
    const float* bo   = (const float*)d_in[4];

    char* ws = (char*)d_ws;
    u16* xb    = (u16*)(ws);                 // 33,554,432 B
    u16* qkv   = (u16*)(ws +  33554432L);    // 100,663,296 B
    u16* ob    = (u16*)(ws + 134217728L);    // 33,554,432 B
    u16* WqkvT = (u16*)(ws + 167772160L);    // 6,291,456 B
    u16* WoutT = (u16*)(ws + 174063616L);    // 2,097,152 B
    const size_t NEEDED = 176160768UL;

    if (ws_size < NEEDED) {
        fill_sentinel<<<2048, 256, 0, stream>>>((float*)d_out, (long)out_size);
        return;
    }

    bool deep = true;
    if (hipFuncSetAttribute(reinterpret_cast<const void*>(&gemm256<0, 16, 12>),
                            hipFuncAttributeMaxDynamicSharedMemorySize,
                            131072) != hipSuccess) deep = false;
    if (hipFuncSetAttribute(reinterpret_cast<const void*>(&gemm256<1, 16, 4>),
                            hipFuncAttributeMaxDynamicSharedMemorySize,
                            131072) != hipSuccess) deep = false;

    convert_x<<<2048, 256, 0, stream>>>(x, xb, 16777216L);
    transpose_f32_bf16<<<dim3(96, 32), 256, 0, stream>>>(Wqkv, WqkvT, 1024, 3072);
    transpose_f32_bf16<<<dim3(32, 32), 256, 0, stream>>>(Wout, WoutT, 1024, 1024);

    // qkv = x @ Wqkv + bqkv   (M=16384, N=3072, K=1024)
    if (deep)
        gemm256<0, 16, 12><<<768, 512, 131072, stream>>>(xb, WqkvT, bq, qkv,
                                                         3072, 1024);
    else
        gemm_bt_bias<0><<<dim3(24, 128), 256, 0, stream>>>(xb, WqkvT, bq, qkv,
                                                           16384, 3072, 1024);

    attn_blocks<<<4096, 64, 0, stream>>>(qkv, ob);

    // out = o @ Wout + bout   (M=16384, N=1024, K=1024)
    if (deep)
        gemm256<1, 16, 4><<<256, 512, 131072, stream>>>(ob, WoutT, bo, d_out,
                                                        1024, 1024);
    else
        gemm_bt_bias<1><<<dim3(8, 128), 256, 0, stream>>>(ob, WoutT, bo, d_out,
                                                          16384, 1024, 1024);
}

// Round 9
// 190.788 us; speedup vs baseline: 1.2043x; 1.0856x over previous
//
#include <hip/hip_runtime.h>
#include <stdint.h>

typedef unsigned short u16;
typedef __attribute__((ext_vector_type(8))) short s16x8;   // 8 x bf16 (4 VGPRs)
typedef __attribute__((ext_vector_type(4))) float f32x4;   // MFMA accumulator

__device__ __forceinline__ f32x4 mfma16x16(s16x8 a, s16x8 b, f32x4 c) {
    return __builtin_amdgcn_mfma_f32_16x16x32_bf16(a, b, c, 0, 0, 0);
}

__device__ __forceinline__ u16 f2bf(float f) {
    union { float f; unsigned u; } c; c.f = f;
    unsigned u = c.u;
    return (u16)((u + 0x7FFFu + ((u >> 16) & 1u)) >> 16);   // RNE
}

// global -> LDS direct 16B load. LDS dest = wave-uniform base + lane*16.
__device__ __forceinline__ void gload16(const void* g, void* l) {
    auto gp = (const __attribute__((address_space(1))) unsigned int*)(g);
    auto lp = (__attribute__((address_space(3))) unsigned int*)(l);
    __builtin_amdgcn_global_load_lds(gp, lp, 16, 0, 0);
}

__device__ __forceinline__ void wave_sync() {
    __builtin_amdgcn_sched_barrier(0);
    asm volatile("s_waitcnt vmcnt(0) lgkmcnt(0)" ::: "memory");
    __builtin_amdgcn_sched_barrier(0);
    __builtin_amdgcn_s_barrier();
    __builtin_amdgcn_sched_barrier(0);
}

// ---------------------------------------------------------------------------
__global__ __launch_bounds__(256) void convert_x(
    const float* __restrict__ src, u16* __restrict__ dst, long n)
{
    const long stride = (long)gridDim.x * 256 * 8;
    for (long i = ((long)blockIdx.x * 256 + threadIdx.x) * 8; i < n; i += stride) {
        const float4 a = *(const float4*)(src + i);
        const float4 b = *(const float4*)(src + i + 4);
        u16 o[8] = { f2bf(a.x), f2bf(a.y), f2bf(a.z), f2bf(a.w),
                     f2bf(b.x), f2bf(b.y), f2bf(b.z), f2bf(b.w) };
        *(s16x8*)(dst + i) = *(const s16x8*)o;
    }
}

__global__ __launch_bounds__(256) void fill_sentinel(float* __restrict__ o, long n)
{
    const long stride = (long)gridDim.x * 256;
    for (long i = (long)blockIdx.x * 256 + threadIdx.x; i < n; i += stride)
        o[i] = 1.0f;
}

__global__ __launch_bounds__(256) void transpose_f32_bf16(
    const float* __restrict__ in, u16* __restrict__ out, int R, int C)
{
    __shared__ u16 t[32][33];
    const int c0 = blockIdx.x * 32, r0 = blockIdx.y * 32;
    const int tx = threadIdx.x & 31, ty = threadIdx.x >> 5;
#pragma unroll
    for (int i = 0; i < 32; i += 8)
        t[ty + i][tx] = f2bf(in[(long)(r0 + ty + i) * C + c0 + tx]);
    __syncthreads();
#pragma unroll
    for (int i = 0; i < 32; i += 8)
        out[(long)(c0 + ty + i) * R + r0 + tx] = t[tx][ty + i];
}

// ---------------------------------------------------------------------------
// 256x256 GEMM, BK=64 dbuf pipeline with REGISTER-LEVEL fragment prefetch.
// R9 change vs R8 (schedule only; traffic layout kept):
//  * each MFMA cluster runs with the NEXT phase's ds_reads in flight
//    (compiler's exact counted lgkm waits); read->use distance = 1 phase.
//  * intra-tile barriers removed: 2 barriers/tile (mid WAR-guard + boundary).
//  * counted vmcnt(4) boundary gate kept (t+1 proven landed; tail vmcnt(0)).
// Phases (tile t, buffer ab=(t&1)):
//  ph0: rd B.kk0(4)+A03.kk0(4)+A47.kk0(4); STA(t+1,h1); MFMA0(A03*B kk0)
//  ph1: rd B.kk1(4)+A03.kk1(4);            STB(t+1,h1); MFMA1(A47*B kk0); BAR
//  ph2: rd A47.kk1(4);                     STA(t+2,h0); MFMA2(A03*B kk1)
//  ph3:                                    STB(t+2,h0); MFMA3(A47*B kk1)
//  gate vmcnt(4); BAR
// WAR: kk0-region reads drained before MFMA1 (auto-lgkm) -> mid BAR ->
//      ph2/ph3 DMA into kk0 region safe. kk1-region staged only after the
//      boundary BAR (next tile), its reads drained before MFMA2/3.
// ---------------------------------------------------------------------------
template <int FP32OUT, int NT, int NBN>
__global__ __launch_bounds__(512, 2) void gemm256(
    const u16* __restrict__ A, const u16* __restrict__ BT,
    const float* __restrict__ bias, void* __restrict__ Cout,
    int N, int K)
{
    extern __shared__ char smem[];          // 131072 B
    char* const As = smem;                  // [(t&1)*2 + h] * 16384
    char* const Bs = smem + 65536;

    const int tid  = threadIdx.x;
    const int lane = tid & 63;
    const int wid  = tid >> 6;
    const int rr   = lane & 15, g = lane >> 4;
    const int wr   = wid >> 2;        // 0..1  (M)
    const int wc   = wid & 3;         // 0..3  (N)

    const int nwg = gridDim.x;
    const int gsw = (blockIdx.x & 7) * (nwg >> 3) + (blockIdx.x >> 3);
    const long m0 = (long)(gsw / NBN) * 256;   // n-fastest within XCD
    const long n0 = (long)(gsw % NBN) * 256;

    // staging: thread covers row (tid>>2)+r*128, 16B chunk cl (pre-swizzled)
    const int cl = (tid & 3) ^ ((tid >> 3) & 3);
    const u16* pA0 = A  + (m0 + (tid >> 2)) * (long)K + cl * 8;
    const u16* pA1 = pA0 + 128 * (long)K;
    const u16* pB0 = BT + (n0 + (tid >> 2)) * (long)K + cl * 8;
    const u16* pB1 = pB0 + 128 * (long)K;
    const int sdst = wid * 1024;

    // fragment read: row*64 + swizzled 16B chunk
    const int xg    = (g ^ ((rr >> 1) & 3)) << 4;
    const int arow  = (wr * 128 + rr) * 64 + xg;   // + mf*1024
    const int brow  = (wc * 64  + rr) * 64 + xg;   // + nf*1024

#define STA(tt, h) { const long c_ = (long)(tt) * 64 + (h) * 32;              \
        char* d_ = As + (((tt) & 1) * 2 + (h)) * 16384 + sdst;                \
        gload16(pA0 + c_, d_); gload16(pA1 + c_, d_ + 8192); }
#define STB(tt, h) { const long c_ = (long)(tt) * 64 + (h) * 32;              \
        char* d_ = Bs + (((tt) & 1) * 2 + (h)) * 16384 + sdst;                \
        gload16(pB0 + c_, d_); gload16(pB1 + c_, d_ + 8192); }
#define SB() __builtin_amdgcn_sched_barrier(0)

    f32x4 acc[8][4] = {};

    // prologue: t0.Ah0, t0.Bh0, t0.Ah1, t0.Bh1, t1.Ah0, t1.Bh0
    STA(0, 0); STB(0, 0); STA(0, 1); STB(0, 1); STA(1, 0); STB(1, 0);
    asm volatile("s_waitcnt vmcnt(4)" ::: "memory");   // t0 fully landed
    SB(); __builtin_amdgcn_s_barrier(); SB();

    for (int t = 0; t < NT; ++t) {
        const int ab = (t & 1) * 32768;
        s16x8 fB0[4], fA0[4], fA1[4], fB1[4], fA2[4], fA3[4];

        // ---- ph0: issue kk0 reads (12); stage (t+1).h1-A; MFMA0
#pragma unroll
        for (int n = 0; n < 4; ++n)
            fB0[n] = *(const s16x8*)(Bs + ab + brow + n * 1024);
#pragma unroll
        for (int m = 0; m < 4; ++m)
            fA0[m] = *(const s16x8*)(As + ab + arow + m * 1024);
#pragma unroll
        for (int m = 0; m < 4; ++m)
            fA1[m] = *(const s16x8*)(As + ab + arow + (m + 4) * 1024);
        if (t + 1 < NT) STA(t + 1, 1);
        SB();
        __builtin_amdgcn_s_setprio(1);
#pragma unroll
        for (int m = 0; m < 4; ++m)
#pragma unroll
            for (int n = 0; n < 4; ++n)
                acc[m][n] = mfma16x16(fA0[m], fB0[n], acc[m][n]);
        __builtin_amdgcn_s_setprio(0);
        SB();

        // ---- ph1: issue kk1 reads (8); stage (t+1).h1-B; MFMA1; mid BAR
#pragma unroll
        for (int n = 0; n < 4; ++n)
            fB1[n] = *(const s16x8*)(Bs + ab + 16384 + brow + n * 1024);
#pragma unroll
        for (int m = 0; m < 4; ++m)
            fA2[m] = *(const s16x8*)(As + ab + 16384 + arow + m * 1024);
        if (t + 1 < NT) STB(t + 1, 1);
        SB();
        __builtin_amdgcn_s_setprio(1);
#pragma unroll
        for (int m = 0; m < 4; ++m)
#pragma unroll
            for (int n = 0; n < 4; ++n)
                acc[m + 4][n] = mfma16x16(fA1[m], fB0[n], acc[m + 4][n]);
        __builtin_amdgcn_s_setprio(0);
        SB(); __builtin_amdgcn_s_barrier(); SB();   // kk0 region now free

        // ---- ph2: issue kk1 A47 reads (4); stage (t+2).h0-A; MFMA2
#pragma unroll
        for (int m = 0; m < 4; ++m)
            fA3[m] = *(const s16x8*)(As + ab + 16384 + arow + (m + 4) * 1024);
        if (t + 2 < NT) STA(t + 2, 0);
        SB();
        __builtin_amdgcn_s_setprio(1);
#pragma unroll
        for (int m = 0; m < 4; ++m)
#pragma unroll
            for (int n = 0; n < 4; ++n)
                acc[m][n] = mfma16x16(fA2[m], fB1[n], acc[m][n]);
        __builtin_amdgcn_s_setprio(0);
        SB();

        // ---- ph3: stage (t+2).h0-B; MFMA3
        if (t + 2 < NT) STB(t + 2, 0);
        SB();
        __builtin_amdgcn_s_setprio(1);
#pragma unroll
        for (int m = 0; m < 4; ++m)
#pragma unroll
            for (int n = 0; n < 4; ++n)
                acc[m + 4][n] = mfma16x16(fA3[m], fB1[n], acc[m + 4][n]);
        __builtin_amdgcn_s_setprio(0);
        SB();

        // ---- boundary: counted gate (t+1 proven landed), barrier
        if (t < NT - 1) {
            if (t >= NT - 2) { asm volatile("s_waitcnt vmcnt(0)" ::: "memory"); }
            else             { asm volatile("s_waitcnt vmcnt(4)" ::: "memory"); }
            SB(); __builtin_amdgcn_s_barrier(); SB();
        }
    }
#undef STA
#undef STB
#undef SB

    // epilogue: n innermost (L2 write-merge)
    float bv[4];
#pragma unroll
    for (int n = 0; n < 4; ++n)
        bv[n] = bias[n0 + wc * 64 + n * 16 + rr];
#pragma unroll
    for (int m = 0; m < 8; ++m) {
        const long rb = m0 + wr * 128 + m * 16 + g * 4;
#pragma unroll
        for (int r = 0; r < 4; ++r) {
            const long rowoff = (rb + r) * N + n0 + wc * 64 + rr;
#pragma unroll
            for (int n = 0; n < 4; ++n) {
                const float v = acc[m][n][r] + bv[n];
                if (FP32OUT) ((float*)Cout)[rowoff + n * 16] = v;
                else         ((u16*)Cout)[rowoff + n * 16] = f2bf(v);
            }
        }
    }
}

// ---------------------------------------------------------------------------
// Fallback GEMM (proven R4 path): 128x128 tile, BK=64, 2-barrier loop.
// ---------------------------------------------------------------------------
template <int FP32OUT>
__global__ __launch_bounds__(256) void gemm_bt_bias(
    const u16* __restrict__ A, const u16* __restrict__ BT,
    const float* __restrict__ bias, void* __restrict__ Cout,
    int M, int N, int K)
{
    __shared__ u16 As[128 * 64];
    __shared__ u16 Bs[128 * 64];
    const int tid  = threadIdx.x;
    const int lane = tid & 63;
    const int wid  = tid >> 6;
    const int rr   = lane & 15, g = lane >> 4;
    const int wm   = (wid >> 1) << 6;
    const int wn   = (wid & 1) << 6;
    const long m0  = (long)blockIdx.y * 128;
    const long n0  = (long)blockIdx.x * 128;
    const int srow   = tid >> 3;
    const int schunk = (tid & 7) ^ (srow & 7);

    f32x4 acc[4][4] = {};

    for (int k0 = 0; k0 < K; k0 += 64) {
#pragma unroll
        for (int q = 0; q < 4; ++q) {
            const int row = q * 32 + srow;
            gload16(A  + (m0 + row) * K + k0 + schunk * 8,
                    (char*)As + q * 4096 + wid * 1024);
            gload16(BT + (n0 + row) * K + k0 + schunk * 8,
                    (char*)Bs + q * 4096 + wid * 1024);
        }
        __syncthreads();
#pragma unroll
        for (int kk = 0; kk < 2; ++kk) {
            s16x8 af[4], bfr[4];
#pragma unroll
            for (int i = 0; i < 4; ++i) {
                const int rowa = wm + i * 16 + rr;
                af[i] = *(const s16x8*)((const char*)As + rowa * 128 +
                         ((kk * 64 + g * 16) ^ ((rowa & 7) << 4)));
                const int rowb = wn + i * 16 + rr;
                bfr[i] = *(const s16x8*)((const char*)Bs + rowb * 128 +
                         ((kk * 64 + g * 16) ^ ((rowb & 7) << 4)));
            }
#pragma unroll
            for (int i = 0; i < 4; ++i)
#pragma unroll
                for (int j = 0; j < 4; ++j)
                    acc[i][j] = mfma16x16(af[i], bfr[j], acc[i][j]);
        }
        __syncthreads();
    }

#pragma unroll
    for (int i = 0; i < 4; ++i)
#pragma unroll
        for (int r = 0; r < 4; ++r) {
            const long rowg = m0 + wm + i * 16 + g * 4 + r;
#pragma unroll
            for (int j = 0; j < 4; ++j) {
                const long col = n0 + wn + j * 16 + rr;
                const float v = acc[i][j][r] + bias[col];
                if (FP32OUT) ((float*)Cout)[rowg * N + col] = v;
                else         ((u16*)Cout)[rowg * N + col] = f2bf(v);
            }
        }
}

// ---------------------------------------------------------------------------
// Factored attention: one wave per (b, h, p). Attention over NB=64 blocks.
// ---------------------------------------------------------------------------
__global__ __launch_bounds__(64) void attn_blocks(
    const u16* __restrict__ qkv, u16* __restrict__ o)
{
    __shared__ u16 Vlds[64 * 64];
    __shared__ u16 Plds[64 * 72];
    const int bid = blockIdx.x;
    const int b = bid >> 11;
    const int h = (bid >> 7) & 15;
    const int p = bid & 127;
    const int lane = threadIdx.x;
    const int rr = lane & 15, g = lane >> 4;
    const long NSTR = 128L * 3072;
    const long base = ((long)b * 8192 + p) * 3072 + h * 64;

    {
        const int vrow = lane >> 3;
        const int vchunk = (lane & 7) ^ (vrow & 7);
#pragma unroll
        for (int q = 0; q < 8; ++q)
            gload16(qkv + base + (long)(q * 8 + vrow) * NSTR + 2048 + vchunk * 8,
                    (char*)Vlds + q * 1024);
    }

    s16x8 kf[4][2], qf[4][2];
#pragma unroll
    for (int t = 0; t < 4; ++t)
#pragma unroll
        for (int ks = 0; ks < 2; ++ks) {
            const long roff = base + (long)(t * 16 + rr) * NSTR + ks * 32 + g * 8;
            kf[t][ks] = *(const s16x8*)(qkv + roff + 1024);
            qf[t][ks] = *(const s16x8*)(qkv + roff);
        }

    f32x4 T[4][4] = {};
#pragma unroll
    for (int ks = 0; ks < 2; ++ks)
#pragma unroll
        for (int i = 0; i < 4; ++i)
#pragma unroll
            for (int jn = 0; jn < 4; ++jn)
                T[i][jn] = mfma16x16(kf[i][ks], qf[jn][ks], T[i][jn]);

    const float scale = 0.125f;
#pragma unroll
    for (int jn = 0; jn < 4; ++jn) {
        const int n = jn * 16 + rr;
        float pv[16];
        float mx = -3e38f;
#pragma unroll
        for (int i = 0; i < 4; ++i)
#pragma unroll
            for (int r = 0; r < 4; ++r) {
                const int m = i * 16 + g * 4 + r;
                const float s = (m <= n) ? T[i][jn][r] * scale : -3e38f;
                pv[i * 4 + r] = s;
                mx = fmaxf(mx, s);
            }
        mx = fmaxf(mx, __shfl_xor(mx, 16));
        mx = fmaxf(mx, __shfl_xor(mx, 32));
        float sum = 0.f;
#pragma unroll
        for (int t = 0; t < 16; ++t) {
            const float e = (pv[t] > -1e30f) ? __expf(pv[t] - mx) : 0.f;
            pv[t] = e;
            sum += e;
        }
        sum += __shfl_xor(sum, 16);
        sum += __shfl_xor(sum, 32);
        const float inv = 1.f / sum;
#pragma unroll
        for (int i = 0; i < 4; ++i)
#pragma unroll
            for (int rp = 0; rp < 2; ++rp) {
                const int m = i * 16 + g * 4 + rp * 2;
                const unsigned lo = f2bf(pv[i * 4 + rp * 2] * inv);
                const unsigned hi = f2bf(pv[i * 4 + rp * 2 + 1] * inv);
                *(unsigned*)((char*)Plds + n * 144 + m * 2) = lo | (hi << 16);
            }
    }

    wave_sync();

    f32x4 O[4][4] = {};
#pragma unroll
    for (int ks = 0; ks < 2; ++ks) {
        s16x8 pa[4];
#pragma unroll
        for (int in = 0; in < 4; ++in)
            pa[in] = *(const s16x8*)((const char*)Plds +
                      (in * 16 + rr) * 144 + ks * 64 + g * 16);
#pragma unroll
        for (int jd = 0; jd < 4; ++jd) {
            s16x8 vb;
#pragma unroll
            for (int j = 0; j < 8; ++j) {
                const int k = ks * 32 + g * 8 + j;
                const int byte = (k * 128 + (jd * 16 + rr) * 2) ^ ((k & 7) << 4);
                vb[j] = *(const short*)((const char*)Vlds + byte);
            }
#pragma unroll
            for (int in = 0; in < 4; ++in)
                O[in][jd] = mfma16x16(pa[in], vb, O[in][jd]);
        }
    }

    const long obase = ((long)b * 8192 + p) * 1024 + h * 64;
#pragma unroll
    for (int in = 0; in < 4; ++in)
#pragma unroll
        for (int r = 0; r < 4; ++r) {
            const long n = in * 16 + g * 4 + r;
#pragma unroll
            for (int jd = 0; jd < 4; ++jd) {
                const long d = jd * 16 + rr;
                o[obase + n * (128L * 1024) + d] = f2bf(O[in][jd][r]);
            }
        }
}

// ---------------------------------------------------------------------------
extern "C" void kernel_launch(void* const* d_in, const int* in_sizes, int n_in,
                              void* d_out, int out_size, void* d_ws, size_t ws_size,
                              hipStream_t stream) {
    const float* x    = (const float*)d_in[0];
    const float* Wqkv = (const float*)d_in[1];
    const float* bq   = (const float*)d_in[2];
    const float* Wout = (const float*)d_in[3];
    const float* bo   = (const float*)d_in[4];

    char* ws = (char*)d_ws;
    u16* xb    = (u16*)(ws);                 // 33,554,432 B
    u16* qkv   = (u16*)(ws +  33554432L);    // 100,663,296 B
    u16* ob    = (u16*)(ws + 134217728L);    // 33,554,432 B
    u16* WqkvT = (u16*)(ws + 167772160L);    // 6,291,456 B
    u16* WoutT = (u16*)(ws + 174063616L);    // 2,097,152 B
    const size_t NEEDED = 176160768UL;

    if (ws_size < NEEDED) {
        fill_sentinel<<<2048, 256, 0, stream>>>((float*)d_out, (long)out_size);
        return;
    }

    bool deep = true;
    if (hipFuncSetAttribute(reinterpret_cast<const void*>(&gemm256<0, 16, 12>),
                            hipFuncAttributeMaxDynamicSharedMemorySize,
                            131072) != hipSuccess) deep = false;
    if (hipFuncSetAttribute(reinterpret_cast<const void*>(&gemm256<1, 16, 4>),
                            hipFuncAttributeMaxDynamicSharedMemorySize,
                            131072) != hipSuccess) deep = false;

    convert_x<<<2048, 256, 0, stream>>>(x, xb, 16777216L);
    transpose_f32_bf16<<<dim3(96, 32), 256, 0, stream>>>(Wqkv, WqkvT, 1024, 3072);
    transpose_f32_bf16<<<dim3(32, 32), 256, 0, stream>>>(Wout, WoutT, 1024, 1024);

    // qkv = x @ Wqkv + bqkv   (M=16384, N=3072, K=1024)
    if (deep)
        gemm256<0, 16, 12><<<768, 512, 131072, stream>>>(xb, WqkvT, bq, qkv,
                                                         3072, 1024);
    else
        gemm_bt_bias<0><<<dim3(24, 128), 256, 0, stream>>>(xb, WqkvT, bq, qkv,
                                                           16384, 3072, 1024);

    attn_blocks<<<4096, 64, 0, stream>>>(qkv, ob);

    // out = o @ Wout + bout   (M=16384, N=1024, K=1024)
    if (deep)
        gemm256<1, 16, 4><<<256, 512, 131072, stream>>>(ob, WoutT, bo, d_out,
                                                        1024, 1024);
    else
        gemm_bt_bias<1><<<dim3(8, 128), 256, 0, stream>>>(ob, WoutT, bo, d_out,
                                                          16384, 1024, 1024);
}